// Round 1
// baseline (102.057 us; speedup 1.0000x reference)
//
#include <hip/hip_runtime.h>

// LIF recurrence: T=128 timesteps, N neurons (fp32).
//   v = BETA*v + I[t] - GAMMA*s ;  s = (v > 1) ;  v = v*(1-s)
// Outputs concatenated flat: spikes (T*N) | v_mem (T*N) | spikes (T*N).
//
// Memory-bound: 134 MB read + 403 MB write => ~85us floor at 6.3 TB/s.
// Each thread owns 4 neurons (float4); loop over T with unroll-8 so the
// compiler keeps multiple global_load_dwordx4 in flight.
//
// NOTE: spike threshold (v > 1.0f) is a hard decision boundary. To match the
// numpy reference bit-exactly we must replicate its per-op fp32 rounding:
// ((BETA*v + I) - GAMMA*s) with NO fma contraction. __fmul_rn/__fadd_rn/
// __fsub_rn are non-contractible exact IEEE ops. The reset v*(1-s) is exactly
// (s ? 0 : v) since s is 0 or 1.

#define T_STEPS 128
#define BETA_F 0.95f
#define GAMMA_F 0.95f
#define VTH_F 1.0f

__global__ __launch_bounds__(256) void lif_kernel(
    const float4* __restrict__ I4,
    float4* __restrict__ s_out,   // spikes, first copy
    float4* __restrict__ v_out,   // v_mem
    float4* __restrict__ s_out2,  // spikes, second copy
    int n4)                       // N/4
{
    int idx = blockIdx.x * blockDim.x + threadIdx.x;
    if (idx >= n4) return;

    float vx = 0.f, vy = 0.f, vz = 0.f, vw = 0.f;
    float sx = 0.f, sy = 0.f, sz = 0.f, sw = 0.f;

    size_t off = (size_t)idx;
    #pragma unroll 8
    for (int t = 0; t < T_STEPS; ++t, off += (size_t)n4) {
        float4 in = I4[off];

        // v = (BETA*v + I) - GAMMA*s, numpy-exact per-op rounding
        vx = __fsub_rn(__fadd_rn(__fmul_rn(BETA_F, vx), in.x), __fmul_rn(GAMMA_F, sx));
        vy = __fsub_rn(__fadd_rn(__fmul_rn(BETA_F, vy), in.y), __fmul_rn(GAMMA_F, sy));
        vz = __fsub_rn(__fadd_rn(__fmul_rn(BETA_F, vz), in.z), __fmul_rn(GAMMA_F, sz));
        vw = __fsub_rn(__fadd_rn(__fmul_rn(BETA_F, vw), in.w), __fmul_rn(GAMMA_F, sw));

        sx = (vx > VTH_F) ? 1.0f : 0.0f;
        sy = (vy > VTH_F) ? 1.0f : 0.0f;
        sz = (vz > VTH_F) ? 1.0f : 0.0f;
        sw = (vw > VTH_F) ? 1.0f : 0.0f;

        // hard reset: v*(1-s) == (s ? 0 : v) exactly
        vx = (sx != 0.0f) ? 0.0f : vx;
        vy = (sy != 0.0f) ? 0.0f : vy;
        vz = (sz != 0.0f) ? 0.0f : vz;
        vw = (sw != 0.0f) ? 0.0f : vw;

        float4 sv = make_float4(sx, sy, sz, sw);
        float4 vv = make_float4(vx, vy, vz, vw);
        s_out[off]  = sv;
        v_out[off]  = vv;
        s_out2[off] = sv;
    }
}

extern "C" void kernel_launch(void* const* d_in, const int* in_sizes, int n_in,
                              void* d_out, int out_size, void* d_ws, size_t ws_size,
                              hipStream_t stream) {
    const float* I = (const float*)d_in[0];
    float* out = (float*)d_out;

    const int TN = in_sizes[0];        // T * N
    const int N = TN / T_STEPS;
    const int n4 = N / 4;

    float* s0 = out;
    float* vm = out + (size_t)TN;
    float* s1 = out + 2 * (size_t)TN;

    const int block = 256;
    const int grid = (n4 + block - 1) / block;

    lif_kernel<<<grid, block, 0, stream>>>(
        (const float4*)I, (float4*)s0, (float4*)vm, (float4*)s1, n4);
}